// Round 1
// baseline (751.410 us; speedup 1.0000x reference)
//
#include <hip/hip_runtime.h>

#define NN 8192
#define NB 64                  // 64 block-rows/cols of 128
#define NLOWER (NB*(NB+1)/2)   // 2080 lower-tri blocks

typedef __attribute__((ext_vector_type(8))) __bf16 bf16x8;
typedef __attribute__((ext_vector_type(4))) __bf16 bf16x4;
typedef __attribute__((ext_vector_type(4))) float f32x4;

__global__ __launch_bounds__(256) void trimm_kernel(const float* __restrict__ A,
                                                    const float* __restrict__ B,
                                                    float* __restrict__ C) {
  int r = blockIdx.x;
  const int tid = threadIdx.x;

  if (r >= NLOWER) {
    // strict-upper zero-fill block
    int u = r - NLOWER;
    int bi = 0;
    while (u >= NB - 1 - bi) { u -= NB - 1 - bi; ++bi; }
    int bj = bi + 1 + u;
    const size_t base = (size_t)bi * 128 * NN + (size_t)bj * 128;
    float4 z = make_float4(0.f, 0.f, 0.f, 0.f);
    #pragma unroll
    for (int i = 0; i < 16; ++i) {
      int f = tid + 256 * i;
      int row = f >> 5, c4 = f & 31;
      *(float4*)(C + base + (size_t)row * NN + c4 * 4) = z;
    }
    return;
  }

  // heavy-first mapping: d = bi-bj from 63 down to 0
  int d = NB - 1;
  while (r >= NB - d) { r -= NB - d; --d; }
  const int bj = r, bi = r + d;

  __shared__ __bf16 As[128][40];  // [m][k], pad 32->40 (80B stride, 16B-aligned)
  __shared__ __bf16 Bs[128][40];  // [n][k] (transposed during staging)

  const int lane = tid & 63;
  const int wid  = tid >> 6;
  const int wr = wid >> 1, wc = wid & 1;   // 2x2 wave grid, each 64x64
  const int lrow = lane & 15;
  const int kgrp = lane >> 4;

  f32x4 acc[4][4];
  #pragma unroll
  for (int m = 0; m < 4; ++m)
    #pragma unroll
    for (int n = 0; n < 4; ++n) acc[m][n] = (f32x4){0.f, 0.f, 0.f, 0.f};

  const int arow0 = bi * 128, bcol0 = bj * 128;
  const int k_lo = bj * 128, k_hi = (bi + 1) * 128;

  for (int ks = k_lo; ks < k_hi; ks += 32) {
    __syncthreads();
    // ---- stage A tile 128x32 (row-major, k contiguous) ----
    const bool mA = (ks + 31 >= arow0);       // only near the diagonal K-blocks
    #pragma unroll
    for (int i = 0; i < 4; ++i) {
      int s = tid + 256 * i;
      int row = s >> 3, kq = s & 7;
      int grow = arow0 + row;
      const float4 av = *(const float4*)(A + (size_t)grow * NN + ks + kq * 4);
      bf16x4 w;
      #pragma unroll
      for (int c = 0; c < 4; ++c) {
        float f = (&av.x)[c];
        if (mA && (ks + kq * 4 + c > grow)) f = 0.f;   // tril(A): keep k <= i
        w[c] = (__bf16)f;
      }
      *(bf16x4*)(&As[row][kq * 4]) = w;
    }
    // ---- stage B tile 32x128, transposed -> Bs[n][k] ----
    const bool mB = (ks < bcol0 + 128);       // only first K-blocks
    #pragma unroll
    for (int i = 0; i < 4; ++i) {
      int g = tid + 256 * i;
      int n = g & 127, kq = g >> 7;
      int gcol = bcol0 + n;
      bf16x4 w;
      #pragma unroll
      for (int c = 0; c < 4; ++c) {
        int gk = ks + kq * 4 + c;
        float f = B[(size_t)gk * NN + gcol];   // coalesced along n across lanes
        if (mB && (gk < gcol)) f = 0.f;        // tril(B): keep k >= j
        w[c] = (__bf16)f;
      }
      *(bf16x4*)(&Bs[n][kq * 4]) = w;
    }
    __syncthreads();

    bf16x8 a[4], b[4];
    #pragma unroll
    for (int m = 0; m < 4; ++m)
      a[m] = *(const bf16x8*)(&As[wr * 64 + m * 16 + lrow][kgrp * 8]);
    #pragma unroll
    for (int n = 0; n < 4; ++n)
      b[n] = *(const bf16x8*)(&Bs[wc * 64 + n * 16 + lrow][kgrp * 8]);
    #pragma unroll
    for (int m = 0; m < 4; ++m)
      #pragma unroll
      for (int n = 0; n < 4; ++n)
        acc[m][n] = __builtin_amdgcn_mfma_f32_16x16x32_bf16(a[m], b[n], acc[m][n], 0, 0, 0);
  }

  // ---- epilogue: C/D layout col=lane&15, row=(lane>>4)*4+q ----
  const bool diag = (bi == bj);
  #pragma unroll
  for (int m = 0; m < 4; ++m) {
    #pragma unroll
    for (int n = 0; n < 4; ++n) {
      #pragma unroll
      for (int q = 0; q < 4; ++q) {
        int row = arow0 + wr * 64 + m * 16 + kgrp * 4 + q;
        int col = bcol0 + wc * 64 + n * 16 + lrow;
        float v = acc[m][n][q];
        if (diag && col > row) v = 0.f;        // tril(C) on the diagonal block
        C[(size_t)row * NN + col] = v;
      }
    }
  }
}

extern "C" void kernel_launch(void* const* d_in, const int* in_sizes, int n_in,
                              void* d_out, int out_size, void* d_ws, size_t ws_size,
                              hipStream_t stream) {
  const float* A = (const float*)d_in[0];
  const float* B = (const float*)d_in[1];
  float* C = (float*)d_out;
  (void)in_sizes; (void)n_in; (void)out_size; (void)d_ws; (void)ws_size;
  hipLaunchKernelGGL(trimm_kernel, dim3(NB * NB), dim3(256), 0, stream, A, B, C);
}

// Round 2
// 520.891 us; speedup vs baseline: 1.4425x; 1.4425x over previous
//
#include <hip/hip_runtime.h>

#define NN 8192
#define NB 64                  // 64 block-rows/cols of 128
#define NLOWER (NB*(NB+1)/2)   // 2080 lower-tri blocks

typedef __attribute__((ext_vector_type(8))) __bf16 bf16x8;
typedef __attribute__((ext_vector_type(4))) __bf16 bf16x4;
typedef __attribute__((ext_vector_type(4))) float f32x4;

__device__ __forceinline__ void gld_lds16(const void* g, void* l) {
  __builtin_amdgcn_global_load_lds((const __attribute__((address_space(1))) void*)g,
                                   (__attribute__((address_space(3))) void*)l, 16, 0, 0);
}

// ---------- prep: Ab = tril(A) in bf16, row-major [i][k]; only k-block <= i-block written ----------
__global__ __launch_bounds__(256) void prepA(const float* __restrict__ A, __bf16* __restrict__ Ab) {
  int r = blockIdx.x;
  const int tid = threadIdx.x;
  int bi = 0; while (r >= bi + 1) { r -= bi + 1; ++bi; }
  const int bk = r;                          // bk <= bi
  const bool diag = (bi == bk);
  const size_t row0 = (size_t)bi * 128, k0 = (size_t)bk * 128;
  #pragma unroll
  for (int i = 0; i < 8; ++i) {
    int u = tid + 256 * i;                   // 2048 units of 8 elems
    int row = u >> 4, c8 = u & 15;
    size_t grow = row0 + row;
    const float4 v0 = *(const float4*)(A + grow * NN + k0 + c8 * 8);
    const float4 v1 = *(const float4*)(A + grow * NN + k0 + c8 * 8 + 4);
    bf16x8 w;
    #pragma unroll
    for (int c = 0; c < 8; ++c) {
      float f = (c < 4) ? (&v0.x)[c] : (&v1.x)[c - 4];
      if (diag && (k0 + c8 * 8 + c > grow)) f = 0.f;   // tril(A): keep k <= i
      w[c] = (__bf16)f;
    }
    *(bf16x8*)(Ab + grow * NN + k0 + c8 * 8) = w;
  }
}

// ---------- prep: Bt[n][k] = tril(B)^T in bf16 (keep k >= n); only k-block >= n-block written ----------
__global__ __launch_bounds__(256) void prepB(const float* __restrict__ B, __bf16* __restrict__ Bt) {
  __shared__ __bf16 S[128 * 129];            // [n][k], pad 129 -> 2-way max on scatter
  int r = blockIdx.x;
  const int tid = threadIdx.x;
  int kb = 0; while (r >= kb + 1) { r -= kb + 1; ++kb; }
  const int nb = r;                          // kb >= nb
  const bool diag = (kb == nb);
  const size_t k0 = (size_t)kb * 128, n0 = (size_t)nb * 128;
  #pragma unroll
  for (int i = 0; i < 8; ++i) {
    int u = tid + 256 * i;
    int kr = u >> 4, c8 = u & 15;
    size_t gk = k0 + kr;
    const float4 v0 = *(const float4*)(B + gk * NN + n0 + c8 * 8);
    const float4 v1 = *(const float4*)(B + gk * NN + n0 + c8 * 8 + 4);
    #pragma unroll
    for (int c = 0; c < 8; ++c) {
      float f = (c < 4) ? (&v0.x)[c] : (&v1.x)[c - 4];
      int n = c8 * 8 + c;
      if (diag && (kr < n)) f = 0.f;         // tril(B): keep k >= n
      S[n * 129 + kr] = (__bf16)f;           // transpose via LDS scatter
    }
  }
  __syncthreads();
  #pragma unroll
  for (int i = 0; i < 8; ++i) {
    int u = tid + 256 * i;
    int nr = u >> 4, k8 = u & 15;
    bf16x8 w;
    #pragma unroll
    for (int c = 0; c < 8; ++c) w[c] = S[nr * 129 + k8 * 8 + c];
    *(bf16x8*)(Bt + (n0 + nr) * NN + k0 + k8 * 8) = w;
  }
}

// ---------- main GEMM: bf16 operands, K-contiguous, global_load_lds staging (m97 structure) ----------
__global__ __launch_bounds__(256) void trimm(const __bf16* __restrict__ Ab,
                                             const __bf16* __restrict__ Bt,
                                             float* __restrict__ C) {
  int r = blockIdx.x;
  const int tid = threadIdx.x;

  if (r >= NLOWER) {
    // strict-upper zero-fill block
    int u = r - NLOWER;
    int bi = 0;
    while (u >= NB - 1 - bi) { u -= NB - 1 - bi; ++bi; }
    int bj = bi + 1 + u;
    const size_t base = (size_t)bi * 128 * NN + (size_t)bj * 128;
    float4 z = make_float4(0.f, 0.f, 0.f, 0.f);
    #pragma unroll
    for (int i = 0; i < 16; ++i) {
      int f = tid + 256 * i;
      int row = f >> 5, c4 = f & 31;
      *(float4*)(C + base + (size_t)row * NN + c4 * 4) = z;
    }
    return;
  }

  // heavy-first mapping: d = bi-bj from 63 down to 0
  int d = NB - 1;
  while (r >= NB - d) { r -= NB - d; --d; }
  const int bj = r, bi = r + d;

  __shared__ __align__(16) __bf16 As[128 * 32];   // [m][k] linear, 64B rows
  __shared__ __align__(16) __bf16 Bs[128 * 32];   // [n][k] linear

  const int lane = tid & 63;
  const int wid  = tid >> 6;
  const int wr = wid >> 1, wc = wid & 1;
  const int lrow = lane & 15;
  const int kgrp = lane >> 4;

  f32x4 acc[4][4];
  #pragma unroll
  for (int m = 0; m < 4; ++m)
    #pragma unroll
    for (int n = 0; n < 4; ++n) acc[m][n] = (f32x4){0.f, 0.f, 0.f, 0.f};

  const int arow0 = bi * 128, bcol0 = bj * 128;
  const int k_lo = bj * 128, k_hi = (bi + 1) * 128;

  // staging geometry: 128x32 bf16 tile = 8KB; 256 threads x 16B = 4KB/issue; 2 issues
  const int e = tid * 8;                    // element index of this thread's 8 bf16
  const int srow = e >> 5, skl = e & 31;
  const __bf16* aBase = Ab + (size_t)(arow0 + srow) * NN + skl;
  const __bf16* bBase = Bt + (size_t)(bcol0 + srow) * NN + skl;
  char* asl = (char*)As + tid * 16;
  char* bsl = (char*)Bs + tid * 16;

  for (int ks = k_lo; ks < k_hi; ks += 32) {
    gld_lds16(aBase + ks, asl);
    gld_lds16(aBase + ks + (size_t)64 * NN, asl + 4096);
    gld_lds16(bBase + ks, bsl);
    gld_lds16(bBase + ks + (size_t)64 * NN, bsl + 4096);
    __syncthreads();                        // compiler drains vmcnt before barrier

    bf16x8 a[4], b[4];
    #pragma unroll
    for (int m = 0; m < 4; ++m)
      a[m] = *(const bf16x8*)(As + (wr * 64 + m * 16 + lrow) * 32 + kgrp * 8);
    #pragma unroll
    for (int n = 0; n < 4; ++n)
      b[n] = *(const bf16x8*)(Bs + (wc * 64 + n * 16 + lrow) * 32 + kgrp * 8);
    #pragma unroll
    for (int m = 0; m < 4; ++m)
      #pragma unroll
      for (int n = 0; n < 4; ++n)
        acc[m][n] = __builtin_amdgcn_mfma_f32_16x16x32_bf16(a[m], b[n], acc[m][n], 0, 0, 0);
    __syncthreads();                        // all reads done before next overwrite
  }

  const bool diag = (bi == bj);
  #pragma unroll
  for (int m = 0; m < 4; ++m) {
    #pragma unroll
    for (int n = 0; n < 4; ++n) {
      #pragma unroll
      for (int q = 0; q < 4; ++q) {
        int row = arow0 + wr * 64 + m * 16 + kgrp * 4 + q;
        int col = bcol0 + wc * 64 + n * 16 + lrow;
        float v = acc[m][n][q];
        if (diag && col > row) v = 0.f;
        C[(size_t)row * NN + col] = v;
      }
    }
  }
}

// ---------- fallback (round-1 kernel) if ws too small ----------
__global__ __launch_bounds__(256) void trimm_fb(const float* __restrict__ A,
                                                const float* __restrict__ B,
                                                float* __restrict__ C) {
  int r = blockIdx.x;
  const int tid = threadIdx.x;
  if (r >= NLOWER) {
    int u = r - NLOWER;
    int bi = 0;
    while (u >= NB - 1 - bi) { u -= NB - 1 - bi; ++bi; }
    int bj = bi + 1 + u;
    const size_t base = (size_t)bi * 128 * NN + (size_t)bj * 128;
    float4 z = make_float4(0.f, 0.f, 0.f, 0.f);
    #pragma unroll
    for (int i = 0; i < 16; ++i) {
      int f = tid + 256 * i;
      int row = f >> 5, c4 = f & 31;
      *(float4*)(C + base + (size_t)row * NN + c4 * 4) = z;
    }
    return;
  }
  int d = NB - 1;
  while (r >= NB - d) { r -= NB - d; --d; }
  const int bj = r, bi = r + d;
  __shared__ __bf16 As[128][40];
  __shared__ __bf16 Bs[128][40];
  const int lane = tid & 63, wid = tid >> 6;
  const int wr = wid >> 1, wc = wid & 1;
  const int lrow = lane & 15, kgrp = lane >> 4;
  f32x4 acc[4][4];
  #pragma unroll
  for (int m = 0; m < 4; ++m)
    #pragma unroll
    for (int n = 0; n < 4; ++n) acc[m][n] = (f32x4){0.f, 0.f, 0.f, 0.f};
  const int arow0 = bi * 128, bcol0 = bj * 128;
  const int k_lo = bj * 128, k_hi = (bi + 1) * 128;
  for (int ks = k_lo; ks < k_hi; ks += 32) {
    __syncthreads();
    const bool mA = (ks + 31 >= arow0);
    #pragma unroll
    for (int i = 0; i < 4; ++i) {
      int s = tid + 256 * i;
      int row = s >> 3, kq = s & 7;
      int grow = arow0 + row;
      const float4 av = *(const float4*)(A + (size_t)grow * NN + ks + kq * 4);
      bf16x4 w;
      #pragma unroll
      for (int c = 0; c < 4; ++c) {
        float f = (&av.x)[c];
        if (mA && (ks + kq * 4 + c > grow)) f = 0.f;
        w[c] = (__bf16)f;
      }
      *(bf16x4*)(&As[row][kq * 4]) = w;
    }
    const bool mB = (ks < bcol0 + 128);
    #pragma unroll
    for (int i = 0; i < 4; ++i) {
      int g = tid + 256 * i;
      int n = g & 127, kq = g >> 7;
      int gcol = bcol0 + n;
      bf16x4 w;
      #pragma unroll
      for (int c = 0; c < 4; ++c) {
        int gk = ks + kq * 4 + c;
        float f = B[(size_t)gk * NN + gcol];
        if (mB && (gk < gcol)) f = 0.f;
        w[c] = (__bf16)f;
      }
      *(bf16x4*)(&Bs[n][kq * 4]) = w;
    }
    __syncthreads();
    bf16x8 a[4], b[4];
    #pragma unroll
    for (int m = 0; m < 4; ++m)
      a[m] = *(const bf16x8*)(&As[wr * 64 + m * 16 + lrow][kgrp * 8]);
    #pragma unroll
    for (int n = 0; n < 4; ++n)
      b[n] = *(const bf16x8*)(&Bs[wc * 64 + n * 16 + lrow][kgrp * 8]);
    #pragma unroll
    for (int m = 0; m < 4; ++m)
      #pragma unroll
      for (int n = 0; n < 4; ++n)
        acc[m][n] = __builtin_amdgcn_mfma_f32_16x16x32_bf16(a[m], b[n], acc[m][n], 0, 0, 0);
  }
  const bool diag = (bi == bj);
  #pragma unroll
  for (int m = 0; m < 4; ++m)
    #pragma unroll
    for (int n = 0; n < 4; ++n)
      #pragma unroll
      for (int q = 0; q < 4; ++q) {
        int row = arow0 + wr * 64 + m * 16 + kgrp * 4 + q;
        int col = bcol0 + wc * 64 + n * 16 + lrow;
        float v = acc[m][n][q];
        if (diag && col > row) v = 0.f;
        C[(size_t)row * NN + col] = v;
      }
}

extern "C" void kernel_launch(void* const* d_in, const int* in_sizes, int n_in,
                              void* d_out, int out_size, void* d_ws, size_t ws_size,
                              hipStream_t stream) {
  const float* A = (const float*)d_in[0];
  const float* B = (const float*)d_in[1];
  float* C = (float*)d_out;
  (void)in_sizes; (void)n_in; (void)out_size;

  const size_t need = (size_t)NN * NN * sizeof(__bf16) * 2;  // 256 MB
  if (ws_size >= need) {
    __bf16* Ab = (__bf16*)d_ws;
    __bf16* Bt = Ab + (size_t)NN * NN;
    hipLaunchKernelGGL(prepA, dim3(NLOWER), dim3(256), 0, stream, A, Ab);
    hipLaunchKernelGGL(prepB, dim3(NLOWER), dim3(256), 0, stream, B, Bt);
    hipLaunchKernelGGL(trimm, dim3(NB * NB), dim3(256), 0, stream, Ab, Bt, C);
  } else {
    hipLaunchKernelGGL(trimm_fb, dim3(NB * NB), dim3(256), 0, stream, A, B, C);
  }
}

// Round 3
// 516.926 us; speedup vs baseline: 1.4536x; 1.0077x over previous
//
#include <hip/hip_runtime.h>

#define NN 8192
#define NB 64                  // 64 block-rows/cols of 128
#define NLOWER (NB*(NB+1)/2)   // 2080 lower-tri blocks

typedef __attribute__((ext_vector_type(8))) __bf16 bf16x8;
typedef __attribute__((ext_vector_type(4))) __bf16 bf16x4;
typedef __attribute__((ext_vector_type(4))) float f32x4;

__device__ __forceinline__ void gld_lds16(const void* g, void* l) {
  __builtin_amdgcn_global_load_lds((const __attribute__((address_space(1))) void*)g,
                                   (__attribute__((address_space(3))) void*)l, 16, 0, 0);
}

// ---------- prep: Ab = tril(A) in bf16, row-major [i][k]; only k-block <= i-block written ----------
__global__ __launch_bounds__(256) void prepA(const float* __restrict__ A, __bf16* __restrict__ Ab) {
  int r = blockIdx.x;
  const int tid = threadIdx.x;
  int bi = 0; while (r >= bi + 1) { r -= bi + 1; ++bi; }
  const int bk = r;                          // bk <= bi
  const bool diag = (bi == bk);
  const size_t row0 = (size_t)bi * 128, k0 = (size_t)bk * 128;
  #pragma unroll
  for (int i = 0; i < 8; ++i) {
    int u = tid + 256 * i;                   // 2048 units of 8 elems
    int row = u >> 4, c8 = u & 15;
    size_t grow = row0 + row;
    const float4 v0 = *(const float4*)(A + grow * NN + k0 + c8 * 8);
    const float4 v1 = *(const float4*)(A + grow * NN + k0 + c8 * 8 + 4);
    bf16x8 w;
    #pragma unroll
    for (int c = 0; c < 8; ++c) {
      float f = (c < 4) ? (&v0.x)[c] : (&v1.x)[c - 4];
      if (diag && (k0 + c8 * 8 + c > grow)) f = 0.f;   // tril(A): keep k <= i
      w[c] = (__bf16)f;
    }
    *(bf16x8*)(Ab + grow * NN + k0 + c8 * 8) = w;
  }
}

// ---------- prep: Bt[n][k] = tril(B)^T in bf16 (keep k >= n); only k-block >= n-block written ----------
__global__ __launch_bounds__(256) void prepB(const float* __restrict__ B, __bf16* __restrict__ Bt) {
  __shared__ __bf16 S[128 * 129];
  int r = blockIdx.x;
  const int tid = threadIdx.x;
  int kb = 0; while (r >= kb + 1) { r -= kb + 1; ++kb; }
  const int nb = r;                          // kb >= nb
  const bool diag = (kb == nb);
  const size_t k0 = (size_t)kb * 128, n0 = (size_t)nb * 128;
  #pragma unroll
  for (int i = 0; i < 8; ++i) {
    int u = tid + 256 * i;
    int kr = u >> 4, c8 = u & 15;
    size_t gk = k0 + kr;
    const float4 v0 = *(const float4*)(B + gk * NN + n0 + c8 * 8);
    const float4 v1 = *(const float4*)(B + gk * NN + n0 + c8 * 8 + 4);
    #pragma unroll
    for (int c = 0; c < 8; ++c) {
      float f = (c < 4) ? (&v0.x)[c] : (&v1.x)[c - 4];
      int n = c8 * 8 + c;
      if (diag && (kr < n)) f = 0.f;         // tril(B): keep k >= n
      S[n * 129 + kr] = (__bf16)f;
    }
  }
  __syncthreads();
  #pragma unroll
  for (int i = 0; i < 8; ++i) {
    int u = tid + 256 * i;
    int nr = u >> 4, k8 = u & 15;
    bf16x8 w;
    #pragma unroll
    for (int c = 0; c < 8; ++c) w[c] = S[nr * 129 + k8 * 8 + c];
    *(bf16x8*)(Bt + (n0 + nr) * NN + k0 + k8 * 8) = w;
  }
}

// ---------- main GEMM: minimal-2-phase pipeline, swizzled LDS (pre-swizzled per-lane source) ----------
__global__ __launch_bounds__(256) void trimm(const __bf16* __restrict__ Ab,
                                             const __bf16* __restrict__ Bt,
                                             float* __restrict__ C) {
  int r = blockIdx.x;
  const int tid = threadIdx.x;

  if (r >= NLOWER) {
    int u = r - NLOWER;
    int bi = 0;
    while (u >= NB - 1 - bi) { u -= NB - 1 - bi; ++bi; }
    int bj = bi + 1 + u;
    const size_t base = (size_t)bi * 128 * NN + (size_t)bj * 128;
    float4 z = make_float4(0.f, 0.f, 0.f, 0.f);
    #pragma unroll
    for (int i = 0; i < 16; ++i) {
      int f = tid + 256 * i;
      int row = f >> 5, c4 = f & 31;
      *(float4*)(C + base + (size_t)row * NN + c4 * 4) = z;
    }
    return;
  }

  // heavy-first mapping: d = bi-bj from 63 down to 0
  int d = NB - 1;
  while (r >= NB - d) { r -= NB - d; --d; }
  const int bj = r, bi = r + d;

  // LDS: 2 buffers x (A 8KB + B 8KB). Paired-row layout: unit r2 (=row>>1) is 128B
  // holding chunks cp 0..7; position cp stores logical (row = 2*r2+((cp^s)>>2),
  // kchunk = (cp^s)&3) where s = r2&7  ->  conflict-free ds_read_b128.
  __shared__ __align__(16) char lds[2][16384];

  const int lane = tid & 63;
  const int wid  = tid >> 6;
  const int wr = wid >> 1, wc = wid & 1;
  const int lrow = lane & 15;
  const int kgrp = lane >> 4;

  const int arow0 = bi * 128, bcol0 = bj * 128;

  // staging source constants (per-lane pre-swizzled global address)
  const int r2t = tid >> 3, cp = tid & 7, sw = r2t & 7;
  const int cpl = cp ^ sw;
  const int rS  = r2t * 2 + (cpl >> 2);
  const int kcS = cpl & 3;
  const __bf16* aSrc = Ab + (size_t)(arow0 + rS) * NN + kcS * 8;
  const __bf16* bSrc = Bt + (size_t)(bcol0 + rS) * NN + kcS * 8;
  char* const ldst = (char*)lds + tid * 16;

  // ds_read byte offsets (swizzled); invariant over m/n (stride 1024B per frag)
  const int rdlo = lrow >> 1;
  const int chnk = ((((lrow & 1) * 4 + kgrp) ^ (rdlo & 7)) * 16);
  const int baseA = (wr * 32 + rdlo) * 128 + chnk;
  const int baseB = 8192 + (wc * 32 + rdlo) * 128 + chnk;

  f32x4 acc[4][4];
  #pragma unroll
  for (int m = 0; m < 4; ++m)
    #pragma unroll
    for (int n = 0; n < 4; ++n) acc[m][n] = (f32x4){0.f, 0.f, 0.f, 0.f};

  const int k_lo = bj * 128;
  const int nt = (d + 1) * 4;                // K-steps of 32

  // prologue: stage kt=0 into buffer 0
  gld_lds16(aSrc + k_lo, ldst);
  gld_lds16(aSrc + k_lo + (size_t)64 * NN, ldst + 4096);
  gld_lds16(bSrc + k_lo, ldst + 8192);
  gld_lds16(bSrc + k_lo + (size_t)64 * NN, ldst + 12288);
  __syncthreads();                           // drains vmcnt(0) + barrier

  int cur = 0;
  for (int kt = 0; kt < nt; ++kt) {
    if (kt + 1 < nt) {                       // stage next tile into other buffer
      const int ks = k_lo + (kt + 1) * 32;
      char* dst = ldst + (cur ^ 1) * 16384;
      gld_lds16(aSrc + ks, dst);
      gld_lds16(aSrc + ks + (size_t)64 * NN, dst + 4096);
      gld_lds16(bSrc + ks, dst + 8192);
      gld_lds16(bSrc + ks + (size_t)64 * NN, dst + 12288);
    }
    const char* buf = (const char*)lds + cur * 16384;
    bf16x8 a[4], b[4];
    #pragma unroll
    for (int m = 0; m < 4; ++m)
      a[m] = *(const bf16x8*)(buf + baseA + m * 1024);
    #pragma unroll
    for (int n = 0; n < 4; ++n)
      b[n] = *(const bf16x8*)(buf + baseB + n * 1024);
    __builtin_amdgcn_s_setprio(1);
    #pragma unroll
    for (int m = 0; m < 4; ++m)
      #pragma unroll
      for (int n = 0; n < 4; ++n)
        acc[m][n] = __builtin_amdgcn_mfma_f32_16x16x32_bf16(a[m], b[n], acc[m][n], 0, 0, 0);
    __builtin_amdgcn_s_setprio(0);
    __syncthreads();                         // single drain+barrier per K-step (after compute)
    cur ^= 1;
  }

  const bool diag = (bi == bj);
  #pragma unroll
  for (int m = 0; m < 4; ++m) {
    #pragma unroll
    for (int n = 0; n < 4; ++n) {
      #pragma unroll
      for (int q = 0; q < 4; ++q) {
        int row = arow0 + wr * 64 + m * 16 + kgrp * 4 + q;
        int col = bcol0 + wc * 64 + n * 16 + lrow;
        float v = acc[m][n][q];
        if (diag && col > row) v = 0.f;
        C[(size_t)row * NN + col] = v;
      }
    }
  }
}

// ---------- fallback (round-1 kernel) if ws too small ----------
__global__ __launch_bounds__(256) void trimm_fb(const float* __restrict__ A,
                                                const float* __restrict__ B,
                                                float* __restrict__ C) {
  int r = blockIdx.x;
  const int tid = threadIdx.x;
  if (r >= NLOWER) {
    int u = r - NLOWER;
    int bi = 0;
    while (u >= NB - 1 - bi) { u -= NB - 1 - bi; ++bi; }
    int bj = bi + 1 + u;
    const size_t base = (size_t)bi * 128 * NN + (size_t)bj * 128;
    float4 z = make_float4(0.f, 0.f, 0.f, 0.f);
    #pragma unroll
    for (int i = 0; i < 16; ++i) {
      int f = tid + 256 * i;
      int row = f >> 5, c4 = f & 31;
      *(float4*)(C + base + (size_t)row * NN + c4 * 4) = z;
    }
    return;
  }
  int d = NB - 1;
  while (r >= NB - d) { r -= NB - d; --d; }
  const int bj = r, bi = r + d;
  __shared__ __bf16 As[128][40];
  __shared__ __bf16 Bs[128][40];
  const int lane = tid & 63, wid = tid >> 6;
  const int wr = wid >> 1, wc = wid & 1;
  const int lrow = lane & 15, kgrp = lane >> 4;
  f32x4 acc[4][4];
  #pragma unroll
  for (int m = 0; m < 4; ++m)
    #pragma unroll
    for (int n = 0; n < 4; ++n) acc[m][n] = (f32x4){0.f, 0.f, 0.f, 0.f};
  const int arow0 = bi * 128, bcol0 = bj * 128;
  const int k_lo = bj * 128, k_hi = (bi + 1) * 128;
  for (int ks = k_lo; ks < k_hi; ks += 32) {
    __syncthreads();
    const bool mA = (ks + 31 >= arow0);
    #pragma unroll
    for (int i = 0; i < 4; ++i) {
      int s = tid + 256 * i;
      int row = s >> 3, kq = s & 7;
      int grow = arow0 + row;
      const float4 av = *(const float4*)(A + (size_t)grow * NN + ks + kq * 4);
      bf16x4 w;
      #pragma unroll
      for (int c = 0; c < 4; ++c) {
        float f = (&av.x)[c];
        if (mA && (ks + kq * 4 + c > grow)) f = 0.f;
        w[c] = (__bf16)f;
      }
      *(bf16x4*)(&As[row][kq * 4]) = w;
    }
    const bool mB = (ks < bcol0 + 128);
    #pragma unroll
    for (int i = 0; i < 4; ++i) {
      int g = tid + 256 * i;
      int n = g & 127, kq = g >> 7;
      int gcol = bcol0 + n;
      bf16x4 w;
      #pragma unroll
      for (int c = 0; c < 4; ++c) {
        int gk = ks + kq * 4 + c;
        float f = B[(size_t)gk * NN + gcol];
        if (mB && (gk < gcol)) f = 0.f;
        w[c] = (__bf16)f;
      }
      *(bf16x4*)(&Bs[n][kq * 4]) = w;
    }
    __syncthreads();
    bf16x8 a[4], b[4];
    #pragma unroll
    for (int m = 0; m < 4; ++m)
      a[m] = *(const bf16x8*)(&As[wr * 64 + m * 16 + lrow][kgrp * 8]);
    #pragma unroll
    for (int n = 0; n < 4; ++n)
      b[n] = *(const bf16x8*)(&Bs[wc * 64 + n * 16 + lrow][kgrp * 8]);
    #pragma unroll
    for (int m = 0; m < 4; ++m)
      #pragma unroll
      for (int n = 0; n < 4; ++n)
        acc[m][n] = __builtin_amdgcn_mfma_f32_16x16x32_bf16(a[m], b[n], acc[m][n], 0, 0, 0);
  }
  const bool diag = (bi == bj);
  #pragma unroll
  for (int m = 0; m < 4; ++m)
    #pragma unroll
    for (int n = 0; n < 4; ++n)
      #pragma unroll
      for (int q = 0; q < 4; ++q) {
        int row = arow0 + wr * 64 + m * 16 + kgrp * 4 + q;
        int col = bcol0 + wc * 64 + n * 16 + lrow;
        float v = acc[m][n][q];
        if (diag && col > row) v = 0.f;
        C[(size_t)row * NN + col] = v;
      }
}

extern "C" void kernel_launch(void* const* d_in, const int* in_sizes, int n_in,
                              void* d_out, int out_size, void* d_ws, size_t ws_size,
                              hipStream_t stream) {
  const float* A = (const float*)d_in[0];
  const float* B = (const float*)d_in[1];
  float* C = (float*)d_out;
  (void)in_sizes; (void)n_in; (void)out_size;

  const size_t need = (size_t)NN * NN * sizeof(__bf16) * 2;  // 256 MB
  if (ws_size >= need) {
    __bf16* Ab = (__bf16*)d_ws;
    __bf16* Bt = Ab + (size_t)NN * NN;
    hipLaunchKernelGGL(prepA, dim3(NLOWER), dim3(256), 0, stream, A, Ab);
    hipLaunchKernelGGL(prepB, dim3(NLOWER), dim3(256), 0, stream, B, Bt);
    hipLaunchKernelGGL(trimm, dim3(NB * NB), dim3(256), 0, stream, Ab, Bt, C);
  } else {
    hipLaunchKernelGGL(trimm_fb, dim3(NB * NB), dim3(256), 0, stream, A, B, C);
  }
}

// Round 5
// 340.397 us; speedup vs baseline: 2.2075x; 1.5186x over previous
//
#include <hip/hip_runtime.h>

#define NN 8192
#define NB2 32
#define NLOW2 528   // 32*33/2 lower-tri 256-blocks
#define NUP2  496

typedef __attribute__((ext_vector_type(8))) __bf16 bf16x8;
typedef __attribute__((ext_vector_type(4))) float f32x4;

__device__ __forceinline__ void gld_lds16(const void* g, void* l) {
  __builtin_amdgcn_global_load_lds((const __attribute__((address_space(1))) void*)g,
                                   (__attribute__((address_space(3))) void*)l, 16, 0, 0);
}

#define SBAR do { asm volatile("" ::: "memory"); __builtin_amdgcn_s_barrier(); \
                  asm volatile("" ::: "memory"); __builtin_amdgcn_sched_barrier(0); } while(0)
#define WAITVM(N) do { asm volatile("s_waitcnt vmcnt(" #N ")" ::: "memory"); \
                       __builtin_amdgcn_sched_barrier(0); } while(0)

// ---------- prep: Ab = tril(A) bf16 row-major; all 128-blocks in the 256-aligned lower band ----------
__global__ __launch_bounds__(256) void prepA(const float* __restrict__ A, __bf16* __restrict__ Ab) {
  const int r = blockIdx.x;
  const int bi = r >> 6, bk = r & 63;         // 64 x 64 blocks of 128
  if ((bk >> 1) > (bi >> 1)) return;          // outside 256-band
  const int tid = threadIdx.x;
  const size_t row0 = (size_t)bi * 128, k0 = (size_t)bk * 128;
  #pragma unroll
  for (int i = 0; i < 8; ++i) {
    int u = tid + 256 * i;
    int row = u >> 4, c8 = u & 15;
    size_t grow = row0 + row;
    const float4 v0 = *(const float4*)(A + grow * NN + k0 + c8 * 8);
    const float4 v1 = *(const float4*)(A + grow * NN + k0 + c8 * 8 + 4);
    bf16x8 w;
    #pragma unroll
    for (int c = 0; c < 8; ++c) {
      float f = (c < 4) ? (&v0.x)[c] : (&v1.x)[c - 4];
      if (k0 + c8 * 8 + c > grow) f = 0.f;    // tril(A): keep k <= i (always applied)
      w[c] = (__bf16)f;
    }
    *(bf16x8*)(Ab + grow * NN + k0 + c8 * 8) = w;
  }
}

// ---------- prep: Bt[n][k] = tril(B)^T bf16; all 128-blocks in the 256-aligned band ----------
__global__ __launch_bounds__(256) void prepB(const float* __restrict__ B, __bf16* __restrict__ Bt) {
  __shared__ __bf16 S[128 * 129];
  const int r = blockIdx.x;
  const int kb = r >> 6, nb = r & 63;         // 64 x 64 blocks of 128
  if ((kb >> 1) < (nb >> 1)) return;
  const int tid = threadIdx.x;
  const size_t k0 = (size_t)kb * 128, n0 = (size_t)nb * 128;
  #pragma unroll
  for (int i = 0; i < 8; ++i) {
    int u = tid + 256 * i;
    int kr = u >> 4, c8 = u & 15;
    size_t gk = k0 + kr;
    const float4 v0 = *(const float4*)(B + gk * NN + n0 + c8 * 8);
    const float4 v1 = *(const float4*)(B + gk * NN + n0 + c8 * 8 + 4);
    #pragma unroll
    for (int c = 0; c < 8; ++c) {
      float f = (c < 4) ? (&v0.x)[c] : (&v1.x)[c - 4];
      int n = c8 * 8 + c;
      if (gk < n0 + n) f = 0.f;               // tril(B): keep k >= n (always applied)
      S[n * 129 + kr] = (__bf16)f;
    }
  }
  __syncthreads();
  #pragma unroll
  for (int i = 0; i < 8; ++i) {
    int u = tid + 256 * i;
    int nr = u >> 4, k8 = u & 15;
    bf16x8 w;
    #pragma unroll
    for (int c = 0; c < 8; ++c) w[c] = S[nr * 129 + k8 * 8 + c];
    *(bf16x8*)(Bt + (n0 + nr) * NN + k0 + k8 * 8) = w;
  }
}

// ---------- main: 256x256 tile, BK=64, 8 waves, 8-phase counted-vmcnt pipeline ----------
// LDS map (128 KiB): buf p (p=t&1) at p*65536.
//   A half h (rows h*128..+127): h*16384; sub-line s (rows s*64..+63): +s*8192; kk: +kk*4096
//   B half h (cols h*128..+127): 32768 + h*16384; kk subtile: +kk*8192
// Sub-tile interior (R3-proven conflict-free): unit u=localrow>>1, slot = ((row&1)*4+kc) ^ (u&7),
//   byte = u*128 + slot*16. Stage uses linear dest + inverse-swizzled per-lane SOURCE (m173).
__global__ __launch_bounds__(512, 2) void trimm(const __bf16* __restrict__ Ab,
                                                const __bf16* __restrict__ Bt,
                                                float* __restrict__ C) {
  int r = blockIdx.x;
  const int tid = threadIdx.x;

  if (r >= NLOW2) {                           // strict-upper zero-fill (dispatched last)
    int u = r - NLOW2;
    int bi0 = 0;
    while (u >= NB2 - 1 - bi0) { u -= NB2 - 1 - bi0; ++bi0; }
    int bj0 = bi0 + 1 + u;
    const size_t base = (size_t)bi0 * 256 * NN + (size_t)bj0 * 256;
    float4 z = make_float4(0.f, 0.f, 0.f, 0.f);
    #pragma unroll
    for (int i = 0; i < 32; ++i) {
      int f = tid + 512 * i;
      int row = f >> 6, c4 = f & 63;
      *(float4*)(C + base + (size_t)row * NN + c4 * 4) = z;
    }
    return;
  }

  // heavy-first: d = bi-bj from 31 down to 0
  int d = NB2 - 1;
  while (r >= NB2 - d) { r -= NB2 - d; --d; }
  const int bj = r, bi = r + d;

  __shared__ __align__(16) char lds[131072];

  const int lane = tid & 63;
  const int wid  = tid >> 6;
  const int wr = wid >> 2, wc = wid & 3;      // 2(M) x 4(N) wave grid; per-wave 128x64
  const int lrow = lane & 15;
  const int kgrp = lane >> 4;
  const int tid16 = tid * 16;

  const int arow0 = bi * 256, bcol0 = bj * 256, k_lo = bj * 256;
  const int nkt = (d + 1) * 4;                // K-tiles of 64
  const int niter = (d + 1) * 2;

  // --- staging source decode (inverse-swizzle the GLOBAL address, LDS dest stays linear) ---
  // A lines = [64 rows][64 k]: kkA = tid>>8; within: u=0..31, slot -> logical row/chunk
  const int tA = tid & 255;
  const int uA = tA >> 3, slA = tA & 7;
  const int cA = slA ^ (uA & 7);
  const int rowA = 2 * uA + (cA >> 2);        // 0..63
  const int kcA = cA & 3;
  const int kkA = tid >> 8;                   // 0/1
  const __bf16* aSrcA = Ab + (size_t)(arow0 + rowA) * NN + kkA * 32 + kcA * 8;
  // B lines = [128 rows][32 k]: u=0..63
  const int uB = tid >> 3, slB = tid & 7;
  const int cB = slB ^ (uB & 7);
  const int rowB = 2 * uB + (cB >> 2);        // 0..127
  const int kcB = cB & 3;
  const __bf16* bSrcB = Bt + (size_t)(bcol0 + rowB) * NN + kcB * 8;

  // --- ds_read per-lane swizzled offset (identical form to R3's zero-conflict kernel) ---
  const int rdoff = (lrow >> 1) * 128 + (((((lrow & 1) << 2) | kgrp)) ^ (lrow >> 1)) * 16;
  const int bhalf = wc >> 1;                  // which B half this wave reads

  f32x4 acc[8][4];
  #pragma unroll
  for (int m = 0; m < 8; ++m)
    #pragma unroll
    for (int n = 0; n < 4; ++n) acc[m][n] = (f32x4){0.f, 0.f, 0.f, 0.f};

  // ---------------- prologue: K0 fully (8 lines, oldest) + K1 partial (6 lines) ----------------
  gld_lds16(aSrcA + k_lo,                          lds + tid16);                          // A0 h0 s0
  gld_lds16(aSrcA + k_lo + (size_t)128 * NN,       lds + 16384 + tid16);                  // A0 h1 s0
  gld_lds16(aSrcA + k_lo + (size_t)64 * NN,        lds + 8192 + tid16);                   // A0 h0 s1
  gld_lds16(aSrcA + k_lo + (size_t)192 * NN,       lds + 16384 + 8192 + tid16);           // A0 h1 s1
  gld_lds16(bSrcB + k_lo,                          lds + 32768 + tid16);                  // B0 h0 k0
  gld_lds16(bSrcB + k_lo + 32,                     lds + 32768 + 8192 + tid16);           // B0 h0 k1
  gld_lds16(bSrcB + k_lo + (size_t)128 * NN,       lds + 32768 + 16384 + tid16);          // B0 h1 k0
  gld_lds16(bSrcB + k_lo + (size_t)128 * NN + 32,  lds + 32768 + 16384 + 8192 + tid16);   // B0 h1 k1
  gld_lds16(bSrcB + k_lo + 64,                     lds + 65536 + 32768 + tid16);          // B1 h0 k0
  gld_lds16(bSrcB + k_lo + 64 + 32,                lds + 65536 + 32768 + 8192 + tid16);   // B1 h0 k1
  gld_lds16(aSrcA + k_lo + 64,                     lds + 65536 + tid16);                  // A1 h0 s0
  gld_lds16(aSrcA + k_lo + 64 + (size_t)128 * NN,  lds + 65536 + 16384 + tid16);          // A1 h1 s0
  gld_lds16(bSrcB + k_lo + 64 + (size_t)128 * NN,      lds + 65536 + 32768 + 16384 + tid16);        // B1 h1 k0
  gld_lds16(bSrcB + k_lo + 64 + (size_t)128 * NN + 32, lds + 65536 + 32768 + 16384 + 8192 + tid16); // B1 h1 k1
  WAITVM(6);                                  // K0's 8 lines are the oldest -> complete
  SBAR;

  // ---------------- K loop: 2 quads (K-tiles) per iteration, 4 phases per quad ----------------
#define QUAD(TT, PP) do {                                                                  \
    const int t_ = (TT);                                                                   \
    bf16x8 b_[4][2];                                                                       \
    _Pragma("unroll")                                                                      \
    for (int q = 0; q < 4; ++q) {                                                          \
      bf16x8 a_[2][2];                                                                     \
      if (q == 0) {                                                                        \
        _Pragma("unroll")                                                                  \
        for (int n = 0; n < 4; ++n)                                                        \
          _Pragma("unroll")                                                                \
          for (int kk = 0; kk < 2; ++kk)                                                   \
            b_[n][kk] = *(const bf16x8*)(lds + (PP)*65536 + 32768 + bhalf*16384            \
                                         + kk*8192 + ((wc & 1)*4 + n)*1024 + rdoff);       \
      }                                                                                    \
      _Pragma("unroll")                                                                    \
      for (int j = 0; j < 2; ++j)                                                          \
        _Pragma("unroll")                                                                  \
        for (int kk = 0; kk < 2; ++kk) {                                                   \
          const int m_ = 2*q + j;                                                          \
          a_[j][kk] = *(const bf16x8*)(lds + (PP)*65536 + wr*16384 + (m_>>2)*8192          \
                                       + kk*4096 + (m_&3)*1024 + rdoff);                   \
        }                                                                                  \
      /* staging: P1->A(t+1)s1, P2->B(t+2)h0, P3->A(t+2)s0, P4->B(t+2)h1 */                \
      if (q == 0) { if (t_ + 1 < nkt) {                                                    \
        const __bf16* s0 = aSrcA + (size_t)64*NN + (k_lo + (t_+1)*64);                     \
        gld_lds16(s0,                      lds + ((PP)^1)*65536 + 8192 + tid16);           \
        gld_lds16(s0 + (size_t)128*NN,     lds + ((PP)^1)*65536 + 16384 + 8192 + tid16); } \
      } else if (q == 1) { if (t_ + 2 < nkt) {                                             \
        const __bf16* s0 = bSrcB + (k_lo + (t_+2)*64);                                     \
        gld_lds16(s0,                      lds + (PP)*65536 + 32768 + tid16);              \
        gld_lds16(s0 + 32,                 lds + (PP)*65536 + 32768 + 8192 + tid16); }     \
      } else if (q == 2) { if (t_ + 2 < nkt) {                                             \
        const __bf16* s0 = aSrcA + (k_lo + (t_+2)*64);                                     \
        gld_lds16(s0,                      lds + (PP)*65536 + tid16);                      \
        gld_lds16(s0 + (size_t)128*NN,     lds + (PP)*65536 + 16384 + tid16); }            \
      } else { if (t_ + 2 < nkt) {                                                         \
        const __bf16* s0 = bSrcB + (size_t)128*NN + (k_lo + (t_+2)*64);                    \
        gld_lds16(s0,                      lds + (PP)*65536 + 32768 + 16384 + tid16);      \
        gld_lds16(s0 + 32,                 lds + (PP)*65536 + 32768 + 16384 + 8192 + tid16); } \
      }                                                                                    \
      SBAR;                                                                                \
      __builtin_amdgcn_s_setprio(1);                                                       \
      _Pragma("unroll")                                                                    \
      for (int j = 0; j < 2; ++j)                                                          \
        _Pragma("unroll")                                                                  \
        for (int n = 0; n < 4; ++n)                                                        \
          _Pragma("unroll")                                                                \
          for (int kk = 0; kk < 2; ++kk)                                                   \
            acc[2*q+j][n] = __builtin_amdgcn_mfma_f32_16x16x32_bf16(                       \
                a_[j][kk], b_[n][kk], acc[2*q+j][n], 0, 0, 0);                             \
      __builtin_amdgcn_s_setprio(0);                                                       \
      if (q == 3) { if (t_ + 2 < nkt) { WAITVM(6); } else { WAITVM(0); } }                 \
      SBAR;                                                                                \
    }                                                                                      \
  } while (0)

  for (int it = 0; it < niter; ++it) {
    QUAD(2 * it, 0);
    QUAD(2 * it + 1, 1);
  }
#undef QUAD

  // ---------------- epilogue ----------------
  const bool diag = (bi == bj);
  #pragma unroll
  for (int m = 0; m < 8; ++m) {
    #pragma unroll
    for (int n = 0; n < 4; ++n) {
      #pragma unroll
      for (int qq = 0; qq < 4; ++qq) {
        int row = arow0 + wr * 128 + m * 16 + kgrp * 4 + qq;
        int col = bcol0 + wc * 64 + n * 16 + lrow;
        float v = acc[m][n][qq];
        if (diag && col > row) v = 0.f;
        C[(size_t)row * NN + col] = v;
      }
    }
  }
}

extern "C" void kernel_launch(void* const* d_in, const int* in_sizes, int n_in,
                              void* d_out, int out_size, void* d_ws, size_t ws_size,
                              hipStream_t stream) {
  const float* A = (const float*)d_in[0];
  const float* B = (const float*)d_in[1];
  float* C = (float*)d_out;
  (void)in_sizes; (void)n_in; (void)out_size; (void)ws_size;

  __bf16* Ab = (__bf16*)d_ws;
  __bf16* Bt = Ab + (size_t)NN * NN;
  hipLaunchKernelGGL(prepA, dim3(64 * 64), dim3(256), 0, stream, A, Ab);
  hipLaunchKernelGGL(prepB, dim3(64 * 64), dim3(256), 0, stream, B, Bt);
  hipLaunchKernelGGL(trimm, dim3(NLOW2 + NUP2), dim3(512), 0, stream, Ab, Bt, C);
}